// Round 17
// baseline (26.509 us; speedup 1.0000x reference)
//
#include <hip/hip_runtime.h>

// Sequential implicit-midpoint solve: y_k = y_{k-1} + DT*f_k - DT*tanh(W s_k),
// s_k = (y_k + y_{k-1})/2, one wave per batch element.
//
// R17: D-layout-resident round — ONE LDS trip (R15 had two; they were ~55%).
// Verified D-layout (R15): lane l, acc_t reg j = u_{chain 4*(l>>4)+j}[16t+(l&15)].
// So lane q<16 holds ALL 4 step-chains' u at comps {16t+q}; lane 16+q holds
// the preview chain (reg 0) at the same comps. Therefore:
//   - tanh + exact corrections run IN D-layout, fully lane-local per comp
//     (4 dependent fmas; yprev is comp-indexed -> no cross-lane prefix).
//   - preview tanh: one ds_swizzle xor-16 (0x401F), consumed next round.
//   - next round's midpoints (5 chains x 4 comps) computed per-comp, packed
//     (DPP neighbor + cvt_pkrtz) and written by 8 even lanes to LDS layout
//     dword[pair m][chain c] (= h2(s_c[2m], s_c[2m+1]) at m*8+c);
//     A-frags read back as 2x ds_read_b32 per frag (2-way bank max = free).
// Garbage containment: A rows 5..15 pollute only D rows 5..15 (unused);
// lanes >=16 scalar state diverges but is masked from writes/stores.
// Numerics = R13/R15 verbatim (r-form): absmax ~0.0434.
// W pre-scaled by 2*log2(e): tanh(Ws) = 1 - 2/(exp2(u)+1).

#define SDIM 64
#define DT_C 0.05f
#define WSCALE 2.8853900817779268f  // 2*log2(e)

typedef _Float16 v4h __attribute__((ext_vector_type(4)));
typedef float    v4f __attribute__((ext_vector_type(4)));
typedef __fp16   g2  __attribute__((ext_vector_type(2)));

#if defined(__HIP_DEVICE_COMPILE__)
#define MFMA16(A, B, C) __builtin_amdgcn_mfma_f32_16x16x16f16((A), (B), (C), 0, 0, 0)
#else
#define MFMA16(A, B, C) (C)  // host pass parses only
#endif

union H2U  { int i; g2 g; };
union V4HU { int2 i2; v4h h; g2 g[2]; };

__device__ __forceinline__ float recip_fast(float x) {
    float r; asm("v_rcp_f32 %0, %1" : "=v"(r) : "v"(x)); return r;
}
__device__ __forceinline__ float exp2_fast(float x) {
    float r; asm("v_exp_f32 %0, %1" : "=v"(r) : "v"(x)); return r;
}
__device__ __forceinline__ int pack_h2i(float a, float b) {
    H2U u; u.g = __builtin_amdgcn_cvt_pkrtz(a, b); return u.i;
}
__device__ __forceinline__ v4h pack_h4(float a, float b, float c, float d) {
    V4HU u;
    u.g[0] = __builtin_amdgcn_cvt_pkrtz(a, b);
    u.g[1] = __builtin_amdgcn_cvt_pkrtz(c, d);
    return u.h;
}
__device__ __forceinline__ v4h i2_as_h4(int a, int b) {
    V4HU u; u.i2 = make_int2(a, b); return u.h;
}
__device__ __forceinline__ int dpp_nb(float s) {
    // quad_perm [1,0,3,2]: lane l <-> l^1
    return __builtin_amdgcn_update_dpp(0, __float_as_int(s), 0xB1, 0xF, 0xF, true);
}

// 16 MFMAs: ac_t += sum_h A(af[h]) * B(wb[t*4+h])  (R15-verified roles)
#define MFMA_BLOCK(ac0, ac1, ac2, ac3, af, wb)                              \
    ac0 = MFMA16(af[0], wb[0],  ac0);  ac1 = MFMA16(af[0], wb[4],  ac1);    \
    ac2 = MFMA16(af[0], wb[8],  ac2);  ac3 = MFMA16(af[0], wb[12], ac3);    \
    ac0 = MFMA16(af[1], wb[1],  ac0);  ac1 = MFMA16(af[1], wb[5],  ac1);    \
    ac2 = MFMA16(af[1], wb[9],  ac2);  ac3 = MFMA16(af[1], wb[13], ac3);    \
    ac0 = MFMA16(af[2], wb[2],  ac0);  ac1 = MFMA16(af[2], wb[6],  ac1);    \
    ac2 = MFMA16(af[2], wb[10], ac2);  ac3 = MFMA16(af[2], wb[14], ac3);    \
    ac0 = MFMA16(af[3], wb[3],  ac0);  ac1 = MFMA16(af[3], wb[7],  ac1);    \
    ac2 = MFMA16(af[3], wb[11], ac2);  ac3 = MFMA16(af[3], wb[15], ac3)

__global__ __launch_bounds__(64) void rnes_dl_kernel(
    const float* __restrict__ y0,
    const float* __restrict__ forces,
    const float* __restrict__ W,
    float* __restrict__ out,
    int n, int B)
{
    const int b = blockIdx.x;
    const int l = threadIdx.x;
    const int c = l & 15;     // A-row / chain for frag duty; also comp-owner q
    const int g = l >> 4;     // k-block
    const int q = c;          // comp-owner index: owns comps 16t+q (lanes <16)

    // B-operand frags (R15-verified): wb[t*4+h] = W[16t+c][16h+4g+kk], scaled
    v4h wb[16];
    {
        #pragma unroll
        for (int t = 0; t < 4; ++t) {
            #pragma unroll
            for (int h = 0; h < 4; ++h) {
                const float4 v = *reinterpret_cast<const float4*>(
                    W + (16 * t + c) * 64 + 16 * h + 4 * g);
                wb[t * 4 + h] = pack_h4(WSCALE * v.x, WSCALE * v.y,
                                        WSCALE * v.z, WSCALE * v.w);
            }
        }
    }

    __shared__ __align__(16) int lds[256];  // [pair m 0..31][slot 0..7] 1 KB
    #pragma unroll
    for (int i = 0; i < 4; ++i) lds[i * 64 + l] = 0;

    const size_t stride = (size_t)B * SDIM;
    const int cb = b * SDIM + q;          // + 16t

    // comp-owner state (valid on lanes < 16; others harmlessly diverge)
    float yprev[4];
    #pragma unroll
    for (int t = 0; t < 4; ++t) yprev[t] = y0[cb + 16 * t];
    if (l < 16) {
        #pragma unroll
        for (int t = 0; t < 4; ++t) out[cb + 16 * t] = yprev[t];
    }

    // ---- seed: tcar = tanh(W y0); A-frag direct from y0 (all rows equal) ----
    int tsw[4];  // carried tcar bits (f32)
    {
        v4h af[4];
        #pragma unroll
        for (int h = 0; h < 4; ++h) {
            const float4 v = *reinterpret_cast<const float4*>(
                y0 + b * SDIM + 16 * h + 4 * g);
            af[h] = pack_h4(v.x, v.y, v.z, v.w);
        }
        v4f ac0 = {0.f, 0.f, 0.f, 0.f}, ac1 = ac0, ac2 = ac0, ac3 = ac0;
        MFMA_BLOCK(ac0, ac1, ac2, ac3, af, wb);
        // every lane: reg0 = u_seed at comps 16t+(l&15) (chains identical)
        tsw[0] = __float_as_int(fmaf(-2.f, recip_fast(exp2_fast(ac0[0]) + 1.f), 1.f));
        tsw[1] = __float_as_int(fmaf(-2.f, recip_fast(exp2_fast(ac1[0]) + 1.f), 1.f));
        tsw[2] = __float_as_int(fmaf(-2.f, recip_fast(exp2_fast(ac2[0]) + 1.f), 1.f));
        tsw[3] = __float_as_int(fmaf(-2.f, recip_fast(exp2_fast(ac3[0]) + 1.f), 1.f));
    }

    // force ring: fs[cc][t] = f_{k+cc}[16t+q], cc=0..4 (k=1 initially)
    float fs[5][4];
    #pragma unroll
    for (int cc = 0; cc < 5; ++cc) {
        #pragma unroll
        for (int t = 0; t < 4; ++t)
            fs[cc][t] = (1 + cc < n) ? forces[(size_t)(1 + cc) * stride + cb + 16 * t] : 0.f;
    }

    #pragma unroll 1
    for (int k = 1; k < n; k += 4) {
        // prefetch next round's new forces f_{k+5+j}
        float fn[4][4];
        #pragma unroll
        for (int j = 0; j < 4; ++j) {
            #pragma unroll
            for (int t = 0; t < 4; ++t)
                fn[j][t] = (k + 5 + j < n)
                    ? forces[(size_t)(k + 5 + j) * stride + cb + 16 * t] : 0.f;
        }

        // tcar from carried swizzle (round 1: local seed bits)
        float tcar[4];
        #pragma unroll
        for (int t = 0; t < 4; ++t) tcar[t] = __int_as_float(tsw[t]);

        // midpoints: s_cc = yp + 0.5*DT*(f-tcar); yp += DT*(f-tcar)
        float sv[5][4], yp[4];
        #pragma unroll
        for (int t = 0; t < 4; ++t) yp[t] = yprev[t];
        #pragma unroll
        for (int cc = 0; cc < 5; ++cc) {
            #pragma unroll
            for (int t = 0; t < 4; ++t) {
                const float d = fs[cc][t] - tcar[t];
                sv[cc][t] = fmaf(0.5f * DT_C, d, yp[t]);
                yp[t] = fmaf(DT_C, d, yp[t]);
            }
        }

        // pack pairs (even lane q: own comp 16t+q, neighbor 16t+q+1)
        int pk[5][4];
        #pragma unroll
        for (int cc = 0; cc < 5; ++cc) {
            #pragma unroll
            for (int t = 0; t < 4; ++t)
                pk[cc][t] = pack_h2i(sv[cc][t], __int_as_float(dpp_nb(sv[cc][t])));
        }

        // write: 8 even lanes, per tile: b128 (chains 0..3) + b32 (chain 4)
        if (l < 16 && !(l & 1)) {
            #pragma unroll
            for (int t = 0; t < 4; ++t) {
                const int base = (8 * t + (q >> 1)) * 8;
                *reinterpret_cast<int4*>(&lds[base]) =
                    make_int4(pk[0][t], pk[1][t], pk[2][t], pk[3][t]);
                lds[base + 4] = pk[4][t];
            }
        }
        asm volatile("" ::: "memory");
        __builtin_amdgcn_sched_barrier(0);

        // A-frags: chain slot = c&7 (rows 5..7 zero-pad, 8..15 stale: D rows unused)
        const int slot = c & 7;
        v4h af[4];
        #pragma unroll
        for (int h = 0; h < 4; ++h) {
            const int d0 = lds[(8 * h + 2 * g + 0) * 8 + slot];
            const int d1 = lds[(8 * h + 2 * g + 1) * 8 + slot];
            af[h] = i2_as_h4(d0, d1);
        }

        // MFMA: D rows 0..4 valid
        v4f ac0 = {0.f, 0.f, 0.f, 0.f}, ac1 = ac0, ac2 = ac0, ac3 = ac0;
        MFMA_BLOCK(ac0, ac1, ac2, ac3, af, wb);

        // r = 1/(exp2(u)+1) for all 16 regs (chains 4g+j at comps 16t+c)
        float r0[4], r1[4], r2[4], r3[4];
        #pragma unroll
        for (int j = 0; j < 4; ++j) {
            r0[j] = recip_fast(exp2_fast(ac0[j]) + 1.f);
            r1[j] = recip_fast(exp2_fast(ac1[j]) + 1.f);
            r2[j] = recip_fast(exp2_fast(ac2[j]) + 1.f);
            r3[j] = recip_fast(exp2_fast(ac3[j]) + 1.f);
        }

        // preview tanh (chain 4 = reg0 on lanes 16..31) -> swizzle xor-16
        tsw[0] = __builtin_amdgcn_ds_swizzle(
            __float_as_int(fmaf(-2.f, r0[0], 1.f)), 0x401F);
        tsw[1] = __builtin_amdgcn_ds_swizzle(
            __float_as_int(fmaf(-2.f, r1[0], 1.f)), 0x401F);
        tsw[2] = __builtin_amdgcn_ds_swizzle(
            __float_as_int(fmaf(-2.f, r2[0], 1.f)), 0x401F);
        tsw[3] = __builtin_amdgcn_ds_swizzle(
            __float_as_int(fmaf(-2.f, r3[0], 1.f)), 0x401F);

        // exact corrections (R13 r-form), lane-local per comp; store per step
        float yy[4];
        #pragma unroll
        for (int t = 0; t < 4; ++t) yy[t] = yprev[t];
        #pragma unroll
        for (int j = 0; j < 4; ++j) {
            yy[0] = fmaf(2.f * DT_C, r0[j], fmaf(DT_C, fs[j][0], yy[0]) - DT_C);
            yy[1] = fmaf(2.f * DT_C, r1[j], fmaf(DT_C, fs[j][1], yy[1]) - DT_C);
            yy[2] = fmaf(2.f * DT_C, r2[j], fmaf(DT_C, fs[j][2], yy[2]) - DT_C);
            yy[3] = fmaf(2.f * DT_C, r3[j], fmaf(DT_C, fs[j][3], yy[3]) - DT_C);
            if (l < 16 && k + j < n) {
                float* po = out + (size_t)(k + j) * stride + cb;
                po[0]  = yy[0];
                po[16] = yy[1];
                po[32] = yy[2];
                po[48] = yy[3];
            }
        }
        #pragma unroll
        for (int t = 0; t < 4; ++t) yprev[t] = yy[t];

        // rotate force ring: fs[0] = fs[4] (= f_{k+4}); fs[1..4] = fn[0..3]
        #pragma unroll
        for (int t = 0; t < 4; ++t) fs[0][t] = fs[4][t];
        #pragma unroll
        for (int j = 0; j < 4; ++j) {
            #pragma unroll
            for (int t = 0; t < 4; ++t) fs[j + 1][t] = fn[j][t];
        }
    }
}

extern "C" void kernel_launch(void* const* d_in, const int* in_sizes, int n_in,
                              void* d_out, int out_size, void* d_ws, size_t ws_size,
                              hipStream_t stream) {
    const float* y0     = (const float*)d_in[0];   // (B, S)
    const float* forces = (const float*)d_in[1];   // (n, B, S)
    const float* W      = (const float*)d_in[2];   // (S, S)
    float* out = (float*)d_out;                    // (n, B, S)

    const int BS = in_sizes[0];       // B * S
    const int B  = BS / SDIM;         // 128
    const int n  = in_sizes[1] / BS;  // 65

    rnes_dl_kernel<<<B, SDIM, 0, stream>>>(y0, forces, W, out, n, B);
}

// Round 18
// 17.247 us; speedup vs baseline: 1.5370x; 1.5370x over previous
//
#include <hip/hip_runtime.h>

// Sequential implicit-midpoint solve: y_k = y_{k-1} + DT*f_k - DT*tanh(W s_k),
// s_k = (y_k + y_{k-1})/2, one wave per batch element.
//
// R18 = R15 (best: 17.4us, absmax 0.0434) with ONE change: the two
// sched_barrier(0) fences become sched_barrier(0x7F).
//   mask 0x7F = ALU|VALU|SALU|MFMA|VMEM|VMEM_READ|VMEM_WRITE may cross;
//   DS (0x80) / DS_READ (0x100) / DS_WRITE (0x200) may NOT cross.
// This preserves the R9/R10 correctness requirement (LDS write must precede
// the staged LDS reads — in-order DS pipe within a wave) while letting the
// scheduler sink the non-critical work (global stores, f-prefetch address
// math, ring rotation, correction tails) under the LDS round-trip and MFMA
// latencies. Hypothesis: R15's round costs 2460 cyc vs ~530 critical-path
// because sched_barrier(0) pinned ~40 non-critical ops into serial slots.
//
// Structure (R15, hardware-verified layouts):
//   5-chain round, 4 steps + preview chain (R13 numerics, absmax 0.0434):
//   D[16x64] = S^T(A) @ W^T(B) via 16x mfma_f32_16x16x16f16.
//   A: lane l holds A[l&15][4*(l>>4)+kk]; B: W[16t+(l&15)][16h+4*(l>>4)+kk];
//   D: lane l holds D[4*(l>>4)+j][l&15].
// W pre-scaled by 2*log2(e): tanh(Ws) = 1 - 2/(exp2(u)+1).

#define SDIM 64
#define DT_C 0.05f
#define WSCALE 2.8853900817779268f  // 2*log2(e)
#define SPITCH 36                   // dword pitch per chain region (bank stagger)

// sched_barrier mask: everything EXCEPT DS may cross
#define FENCE_MASK 0x7F

typedef _Float16 v4h __attribute__((ext_vector_type(4)));
typedef float    v4f __attribute__((ext_vector_type(4)));
typedef __fp16   g2  __attribute__((ext_vector_type(2)));

#if defined(__HIP_DEVICE_COMPILE__)
#define MFMA16(A, B, C) __builtin_amdgcn_mfma_f32_16x16x16f16((A), (B), (C), 0, 0, 0)
#else
#define MFMA16(A, B, C) (C)  // host pass parses only
#endif

union H2U  { int i; g2 g; };
union V4HU { int2 i2; v4h h; g2 g[2]; };

__device__ __forceinline__ float recip_fast(float x) {
    float r; asm("v_rcp_f32 %0, %1" : "=v"(r) : "v"(x)); return r;
}
__device__ __forceinline__ float exp2_fast(float x) {
    float r; asm("v_exp_f32 %0, %1" : "=v"(r) : "v"(x)); return r;
}
__device__ __forceinline__ int pack_h2i(float a, float b) {
    H2U u; u.g = __builtin_amdgcn_cvt_pkrtz(a, b); return u.i;
}
__device__ __forceinline__ v4h pack_h4(float a, float b, float c, float d) {
    V4HU u;
    u.g[0] = __builtin_amdgcn_cvt_pkrtz(a, b);
    u.g[1] = __builtin_amdgcn_cvt_pkrtz(c, d);
    return u.h;
}
__device__ __forceinline__ v4h i2_as_h4(int2 v) { V4HU u; u.i2 = v; return u.h; }
__device__ __forceinline__ int dpp_nb(float s) {
    // quad_perm [1,0,3,2]: lane l <-> l^1
    return __builtin_amdgcn_update_dpp(0, __float_as_int(s), 0xB1, 0xF, 0xF, true);
}

// 5-chain matvec round via MFMA: u_c = (W s_c)_lane, c=0..4.
__device__ __forceinline__ void matvec5_mfma(int* lds_s, float* lds_u,
                                             const v4h* __restrict__ wb,
                                             int l,
                                             float s0, float s1, float s2,
                                             float s3, float s4,
                                             float& u0, float& u1, float& u2,
                                             float& u3, float& u4)
{
    const bool odd = (l & 1);
    const int m = l >> 1;

    // packed pair (s_c[2m], s_c[2m+1]) per chain (parity-dependent pack order)
    const float n0 = __int_as_float(dpp_nb(s0));
    const float n1 = __int_as_float(dpp_nb(s1));
    const float n2 = __int_as_float(dpp_nb(s2));
    const float n3 = __int_as_float(dpp_nb(s3));
    const float n4 = __int_as_float(dpp_nb(s4));
    const int p0 = odd ? pack_h2i(n0, s0) : pack_h2i(s0, n0);
    const int p1 = odd ? pack_h2i(n1, s1) : pack_h2i(s1, n1);
    const int p2 = odd ? pack_h2i(n2, s2) : pack_h2i(s2, n2);
    const int p3 = odd ? pack_h2i(n3, s3) : pack_h2i(s3, n3);
    const int p4 = odd ? pack_h2i(n4, s4) : pack_h2i(s4, n4);

    // chain-major layout: dword c*SPITCH + m = h2(s_c[2m], s_c[2m+1])
    if (!odd) {
        lds_s[0 * SPITCH + m] = p0;
        lds_s[1 * SPITCH + m] = p1;
        lds_s[4 * SPITCH + m] = p4;
    } else {
        lds_s[2 * SPITCH + m] = p2;
        lds_s[3 * SPITCH + m] = p3;
    }

    // ---- DS-only fence: s-writes precede A-frag reads; all else may cross ----
    asm volatile("" ::: "memory");
    __builtin_amdgcn_sched_barrier(FENCE_MASK);

    // A-frags: chain c = l&15, comps 16h + 4*(l>>4)..+3 -> ds_read_b64 each
    const int2* s2p = reinterpret_cast<const int2*>(lds_s);
    const int abase = 18 * (l & 15) + (l >> 4);   // int2 units (SPITCH/2 = 18)
    const v4h a0 = i2_as_h4(s2p[abase + 0]);
    const v4h a1 = i2_as_h4(s2p[abase + 4]);
    const v4h a2 = i2_as_h4(s2p[abase + 8]);
    const v4h a3 = i2_as_h4(s2p[abase + 12]);

    // 16 MFMAs: tile t (output comps 16t..16t+15) x K-chunks h=0..3
    v4f c0 = {0.f, 0.f, 0.f, 0.f};
    v4f c1 = c0, c2 = c0, c3 = c0;
    c0 = MFMA16(a0, wb[0],  c0);  c1 = MFMA16(a0, wb[4],  c1);
    c2 = MFMA16(a0, wb[8],  c2);  c3 = MFMA16(a0, wb[12], c3);
    c0 = MFMA16(a1, wb[1],  c0);  c1 = MFMA16(a1, wb[5],  c1);
    c2 = MFMA16(a1, wb[9],  c2);  c3 = MFMA16(a1, wb[13], c3);
    c0 = MFMA16(a2, wb[2],  c0);  c1 = MFMA16(a2, wb[6],  c1);
    c2 = MFMA16(a2, wb[10], c2);  c3 = MFMA16(a2, wb[14], c3);
    c0 = MFMA16(a3, wb[3],  c0);  c1 = MFMA16(a3, wb[7],  c1);
    c2 = MFMA16(a3, wb[11], c2);  c3 = MFMA16(a3, wb[15], c3);

    // redistribution: lanes 0..15 hold chains 0..3 of comp 16t+l in c_t regs;
    // lanes 16..31 hold chain 4 of comp 16t+(l&15) in c_t reg 0.
    if (l < 16) {
        float4* up = reinterpret_cast<float4*>(lds_u);
        up[0 * 16 + l] = make_float4(c0.x, c0.y, c0.z, c0.w);
        up[1 * 16 + l] = make_float4(c1.x, c1.y, c1.z, c1.w);
        up[2 * 16 + l] = make_float4(c2.x, c2.y, c2.z, c2.w);
        up[3 * 16 + l] = make_float4(c3.x, c3.y, c3.z, c3.w);
    } else if (l < 32) {
        const int q = l & 15;
        lds_u[256 + 0 * 16 + q] = c0.x;
        lds_u[256 + 1 * 16 + q] = c1.x;
        lds_u[256 + 2 * 16 + q] = c2.x;
        lds_u[256 + 3 * 16 + q] = c3.x;
    }

    // ---- DS-only fence: u-writes precede u-reads; all else may cross ----
    asm volatile("" ::: "memory");
    __builtin_amdgcn_sched_barrier(FENCE_MASK);

    const float4 uq = reinterpret_cast<const float4*>(lds_u)[l];
    u0 = uq.x; u1 = uq.y; u2 = uq.z; u3 = uq.w;
    u4 = lds_u[256 + l];
}

__global__ __launch_bounds__(64) void rnes_seq_kernel(
    const float* __restrict__ y0,
    const float* __restrict__ forces,
    const float* __restrict__ W,
    float* __restrict__ out,
    int n, int B)
{
    const int b = blockIdx.x;
    const int l = threadIdx.x;  // lane = state component

    // B-operand frags: wb[t*4+h] = W[16t+(l&15)][16h+4*(l>>4)+kk], scaled
    v4h wb[16];
    {
        const int co = l & 15, g = l >> 4;
        #pragma unroll
        for (int t = 0; t < 4; ++t) {
            #pragma unroll
            for (int h = 0; h < 4; ++h) {
                const float4 v = *reinterpret_cast<const float4*>(
                    W + (16 * t + co) * 64 + 16 * h + 4 * g);
                wb[t * 4 + h] = pack_h4(WSCALE * v.x, WSCALE * v.y,
                                        WSCALE * v.z, WSCALE * v.w);
            }
        }
    }

    __shared__ __align__(16) int   lds_s[576];  // 16*SPITCH dwords
    __shared__ __align__(16) float lds_u[320];

    // zero lds_s once: A rows 5..15 then read zeros (deterministic, no NaNs)
    #pragma unroll
    for (int i = 0; i < 9; ++i) lds_s[i * 64 + l] = 0;

    const size_t stride = (size_t)B * SDIM;
    const int off = b * SDIM + l;

    float yprev = y0[off];
    out[off] = yprev;  // out[0] = y0 pass-through

    // Seed tanh carry at s ~= y0
    float u0, u1, u2, u3, u4, tcar;
    matvec5_mfma(lds_s, lds_u, wb, l, yprev, yprev, yprev, yprev, yprev,
                 u0, u1, u2, u3, u4);
    tcar = fmaf(-2.0f, recip_fast(exp2_fast(u0) + 1.0f), 1.0f);

    // force ring fR0..fR4 = f_k..f_{k+4}
    float fR0 = (n > 1) ? forces[1 * stride + off] : 0.f;
    float fR1 = (n > 2) ? forces[2 * stride + off] : 0.f;
    float fR2 = (n > 3) ? forces[3 * stride + off] : 0.f;
    float fR3 = (n > 4) ? forces[4 * stride + off] : 0.f;
    float fR4 = (n > 5) ? forces[5 * stride + off] : 0.f;
    const float* fpre = forces + 6 * stride + off;
    float* op = out + stride + off;

    int k = 1;
    #pragma unroll 1
    for (; k + 3 < n; k += 4) {
        float pf0 = 0.f, pf1 = 0.f, pf2 = 0.f, pf3 = 0.f;
        if (k + 5 < n) pf0 = fpre[0 * stride];
        if (k + 6 < n) pf1 = fpre[1 * stride];
        if (k + 7 < n) pf2 = fpre[2 * stride];
        if (k + 8 < n) pf3 = fpre[3 * stride];
        fpre += 4 * stride;

        // speculative midpoints with carried tanh (R13 numerics, verbatim)
        const float d0 = fR0 - tcar;
        const float s0 = fmaf(0.5f * DT_C, d0, yprev);
        const float yp0 = fmaf(DT_C, d0, yprev);
        const float d1 = fR1 - tcar;
        const float s1 = fmaf(0.5f * DT_C, d1, yp0);
        const float yp1 = fmaf(DT_C, d1, yp0);
        const float d2 = fR2 - tcar;
        const float s2 = fmaf(0.5f * DT_C, d2, yp1);
        const float yp2 = fmaf(DT_C, d2, yp1);
        const float d3 = fR3 - tcar;
        const float s3 = fmaf(0.5f * DT_C, d3, yp2);
        const float yp3 = fmaf(DT_C, d3, yp2);
        const float d4 = fR4 - tcar;
        const float s4 = fmaf(0.5f * DT_C, d4, yp3);  // PREVIEW midpoint k+4

        matvec5_mfma(lds_s, lds_u, wb, l, s0, s1, s2, s3, s4,
                     u0, u1, u2, u3, u4);

        const float r0 = recip_fast(exp2_fast(u0) + 1.0f);
        const float r1 = recip_fast(exp2_fast(u1) + 1.0f);
        const float r2 = recip_fast(exp2_fast(u2) + 1.0f);
        const float r3 = recip_fast(exp2_fast(u3) + 1.0f);
        const float r4 = recip_fast(exp2_fast(u4) + 1.0f);

        // exact-recurrence corrections with fresh tanh
        const float y1c = fmaf(2.0f * DT_C, r0, fmaf(DT_C, fR0, yprev) - DT_C);
        const float y2c = fmaf(2.0f * DT_C, r1, fmaf(DT_C, fR1, y1c) - DT_C);
        const float y3c = fmaf(2.0f * DT_C, r2, fmaf(DT_C, fR2, y2c) - DT_C);
        const float y4c = fmaf(2.0f * DT_C, r3, fmaf(DT_C, fR3, y3c) - DT_C);

        op[0 * stride] = y1c;
        op[1 * stride] = y2c;
        op[2 * stride] = y3c;
        op[3 * stride] = y4c;
        op += 4 * stride;

        yprev = y4c;
        tcar = fmaf(-2.0f, r4, 1.0f);  // preview tanh -> next round's carry
        fR0 = fR4; fR1 = pf0; fR2 = pf1; fR3 = pf2; fR4 = pf3;
    }

    // generic 1-step tail (not hit for n=65)
    #pragma unroll 1
    for (; k < n; ++k) {
        const float s = fmaf(0.5f * DT_C, fR0 - tcar, yprev);
        matvec5_mfma(lds_s, lds_u, wb, l, s, s, s, s, s, u0, u1, u2, u3, u4);
        const float r = recip_fast(exp2_fast(u0) + 1.0f);
        const float y = fmaf(2.0f * DT_C, r, fmaf(DT_C, fR0, yprev) - DT_C);
        *op = y;
        op += stride;
        yprev = y;
        tcar = fmaf(-2.0f, r, 1.0f);
        fR0 = fR1; fR1 = fR2; fR2 = fR3; fR3 = fR4;
    }
}

extern "C" void kernel_launch(void* const* d_in, const int* in_sizes, int n_in,
                              void* d_out, int out_size, void* d_ws, size_t ws_size,
                              hipStream_t stream) {
    const float* y0     = (const float*)d_in[0];   // (B, S)
    const float* forces = (const float*)d_in[1];   // (n, B, S)
    const float* W      = (const float*)d_in[2];   // (S, S)
    float* out = (float*)d_out;                    // (n, B, S)

    const int BS = in_sizes[0];       // B * S
    const int B  = BS / SDIM;         // 128
    const int n  = in_sizes[1] / BS;  // 65

    rnes_seq_kernel<<<B, SDIM, 0, stream>>>(y0, forces, W, out, n, B);
}

// Round 19
// 15.876 us; speedup vs baseline: 1.6697x; 1.0863x over previous
//
#include <hip/hip_runtime.h>

// Sequential implicit-midpoint solve: y_k = y_{k-1} + DT*f_k - DT*tanh(W s_k),
// s_k = (y_k + y_{k-1})/2, one wave per batch element.
//
// R19 = R18 (17.25us, absmax 0.04345703) + ADDRESSING DIET (single change):
//   every global access is uniform_row_ptr[l], where row pointers are
//   wave-uniform (functions of b, k, n only) -> SGPR + saddr-form loads,
//   scalar-pipe pointer walks, and SCALAR row clamps min(row, n-1) instead
//   of vector cmp/cndmask guards. Clamped-garbage flows only into dead slots
//   (final round's preview tanh, prefetches of a nonexistent round).
//   R18's round was ~250-300 emitted instrs at ~8 cyc/instr (solo wave);
//   ~55 of them were 64-bit vector address math + guards. matvec5_mfma is
//   byte-identical to R18 (FENCE 0x7F), so absmax must stay bit-identical.
//
// Structure (hardware-verified): 5-chain round (4 steps + preview, R13
// numerics), D[16x64] = S^T(A) @ W^T(B) via 16x mfma_f32_16x16x16f16.
//   A: lane l holds A[l&15][4*(l>>4)+kk]; B: W[16t+(l&15)][16h+4*(l>>4)+kk];
//   D: lane l holds D[4*(l>>4)+j][l&15].
// W pre-scaled by 2*log2(e): tanh(Ws) = 1 - 2/(exp2(u)+1).

#define SDIM 64
#define DT_C 0.05f
#define WSCALE 2.8853900817779268f  // 2*log2(e)
#define SPITCH 36                   // dword pitch per chain region (bank stagger)
#define FENCE_MASK 0x7F             // DS may not cross; all else may

typedef _Float16 v4h __attribute__((ext_vector_type(4)));
typedef float    v4f __attribute__((ext_vector_type(4)));
typedef __fp16   g2  __attribute__((ext_vector_type(2)));

#if defined(__HIP_DEVICE_COMPILE__)
#define MFMA16(A, B, C) __builtin_amdgcn_mfma_f32_16x16x16f16((A), (B), (C), 0, 0, 0)
#else
#define MFMA16(A, B, C) (C)  // host pass parses only
#endif

union H2U  { int i; g2 g; };
union V4HU { int2 i2; v4h h; g2 g[2]; };

__device__ __forceinline__ float recip_fast(float x) {
    float r; asm("v_rcp_f32 %0, %1" : "=v"(r) : "v"(x)); return r;
}
__device__ __forceinline__ float exp2_fast(float x) {
    float r; asm("v_exp_f32 %0, %1" : "=v"(r) : "v"(x)); return r;
}
__device__ __forceinline__ int pack_h2i(float a, float b) {
    H2U u; u.g = __builtin_amdgcn_cvt_pkrtz(a, b); return u.i;
}
__device__ __forceinline__ v4h pack_h4(float a, float b, float c, float d) {
    V4HU u;
    u.g[0] = __builtin_amdgcn_cvt_pkrtz(a, b);
    u.g[1] = __builtin_amdgcn_cvt_pkrtz(c, d);
    return u.h;
}
__device__ __forceinline__ v4h i2_as_h4(int2 v) { V4HU u; u.i2 = v; return u.h; }
__device__ __forceinline__ int dpp_nb(float s) {
    // quad_perm [1,0,3,2]: lane l <-> l^1
    return __builtin_amdgcn_update_dpp(0, __float_as_int(s), 0xB1, 0xF, 0xF, true);
}
__device__ __forceinline__ int imin(int a, int b) { return a < b ? a : b; }

// 5-chain matvec round via MFMA: u_c = (W s_c)_lane, c=0..4.
// (byte-identical to R18)
__device__ __forceinline__ void matvec5_mfma(int* lds_s, float* lds_u,
                                             const v4h* __restrict__ wb,
                                             int l,
                                             float s0, float s1, float s2,
                                             float s3, float s4,
                                             float& u0, float& u1, float& u2,
                                             float& u3, float& u4)
{
    const bool odd = (l & 1);
    const int m = l >> 1;

    const float n0 = __int_as_float(dpp_nb(s0));
    const float n1 = __int_as_float(dpp_nb(s1));
    const float n2 = __int_as_float(dpp_nb(s2));
    const float n3 = __int_as_float(dpp_nb(s3));
    const float n4 = __int_as_float(dpp_nb(s4));
    const int p0 = odd ? pack_h2i(n0, s0) : pack_h2i(s0, n0);
    const int p1 = odd ? pack_h2i(n1, s1) : pack_h2i(s1, n1);
    const int p2 = odd ? pack_h2i(n2, s2) : pack_h2i(s2, n2);
    const int p3 = odd ? pack_h2i(n3, s3) : pack_h2i(s3, n3);
    const int p4 = odd ? pack_h2i(n4, s4) : pack_h2i(s4, n4);

    if (!odd) {
        lds_s[0 * SPITCH + m] = p0;
        lds_s[1 * SPITCH + m] = p1;
        lds_s[4 * SPITCH + m] = p4;
    } else {
        lds_s[2 * SPITCH + m] = p2;
        lds_s[3 * SPITCH + m] = p3;
    }

    asm volatile("" ::: "memory");
    __builtin_amdgcn_sched_barrier(FENCE_MASK);

    const int2* s2p = reinterpret_cast<const int2*>(lds_s);
    const int abase = 18 * (l & 15) + (l >> 4);
    const v4h a0 = i2_as_h4(s2p[abase + 0]);
    const v4h a1 = i2_as_h4(s2p[abase + 4]);
    const v4h a2 = i2_as_h4(s2p[abase + 8]);
    const v4h a3 = i2_as_h4(s2p[abase + 12]);

    v4f c0 = {0.f, 0.f, 0.f, 0.f};
    v4f c1 = c0, c2 = c0, c3 = c0;
    c0 = MFMA16(a0, wb[0],  c0);  c1 = MFMA16(a0, wb[4],  c1);
    c2 = MFMA16(a0, wb[8],  c2);  c3 = MFMA16(a0, wb[12], c3);
    c0 = MFMA16(a1, wb[1],  c0);  c1 = MFMA16(a1, wb[5],  c1);
    c2 = MFMA16(a1, wb[9],  c2);  c3 = MFMA16(a1, wb[13], c3);
    c0 = MFMA16(a2, wb[2],  c0);  c1 = MFMA16(a2, wb[6],  c1);
    c2 = MFMA16(a2, wb[10], c2);  c3 = MFMA16(a2, wb[14], c3);
    c0 = MFMA16(a3, wb[3],  c0);  c1 = MFMA16(a3, wb[7],  c1);
    c2 = MFMA16(a3, wb[11], c2);  c3 = MFMA16(a3, wb[15], c3);

    if (l < 16) {
        float4* up = reinterpret_cast<float4*>(lds_u);
        up[0 * 16 + l] = make_float4(c0.x, c0.y, c0.z, c0.w);
        up[1 * 16 + l] = make_float4(c1.x, c1.y, c1.z, c1.w);
        up[2 * 16 + l] = make_float4(c2.x, c2.y, c2.z, c2.w);
        up[3 * 16 + l] = make_float4(c3.x, c3.y, c3.z, c3.w);
    } else if (l < 32) {
        const int q = l & 15;
        lds_u[256 + 0 * 16 + q] = c0.x;
        lds_u[256 + 1 * 16 + q] = c1.x;
        lds_u[256 + 2 * 16 + q] = c2.x;
        lds_u[256 + 3 * 16 + q] = c3.x;
    }

    asm volatile("" ::: "memory");
    __builtin_amdgcn_sched_barrier(FENCE_MASK);

    const float4 uq = reinterpret_cast<const float4*>(lds_u)[l];
    u0 = uq.x; u1 = uq.y; u2 = uq.z; u3 = uq.w;
    u4 = lds_u[256 + l];
}

__global__ __launch_bounds__(64) void rnes_seq_kernel(
    const float* __restrict__ y0,
    const float* __restrict__ forces,
    const float* __restrict__ W,
    float* __restrict__ out,
    int n, int B)
{
    const int b = blockIdx.x;
    const int l = threadIdx.x;  // lane = state component

    // B-operand frags: wb[t*4+h] = W[16t+(l&15)][16h+4*(l>>4)+kk], scaled
    v4h wb[16];
    {
        const int co = l & 15, g = l >> 4;
        #pragma unroll
        for (int t = 0; t < 4; ++t) {
            #pragma unroll
            for (int h = 0; h < 4; ++h) {
                const float4 v = *reinterpret_cast<const float4*>(
                    W + (16 * t + co) * 64 + 16 * h + 4 * g);
                wb[t * 4 + h] = pack_h4(WSCALE * v.x, WSCALE * v.y,
                                        WSCALE * v.z, WSCALE * v.w);
            }
        }
    }

    __shared__ __align__(16) int   lds_s[576];
    __shared__ __align__(16) float lds_u[320];
    #pragma unroll
    for (int i = 0; i < 9; ++i) lds_s[i * 64 + l] = 0;

    const int BS = B * SDIM;  // row stride in elements (uniform, 32-bit)

    // wave-uniform row bases (scalar pipe)
    const float* frow = forces + b * SDIM;   // + row*BS
    float*       orow = out    + b * SDIM;

    float yprev = (y0 + b * SDIM)[l];
    orow[l] = yprev;  // out[0] = y0 pass-through

    // Seed tanh carry at s ~= y0
    float u0, u1, u2, u3, u4, tcar;
    matvec5_mfma(lds_s, lds_u, wb, l, yprev, yprev, yprev, yprev, yprev,
                 u0, u1, u2, u3, u4);
    tcar = fmaf(-2.0f, recip_fast(exp2_fast(u0) + 1.0f), 1.0f);

    // force ring fR0..fR4 = f_k..f_{k+4}; scalar-clamped rows (garbage only
    // ever flows into dead slots: final preview / unused prefetch)
    float fR0 = (frow + (size_t)imin(1, n - 1) * BS)[l];
    float fR1 = (frow + (size_t)imin(2, n - 1) * BS)[l];
    float fR2 = (frow + (size_t)imin(3, n - 1) * BS)[l];
    float fR3 = (frow + (size_t)imin(4, n - 1) * BS)[l];
    float fR4 = (frow + (size_t)imin(5, n - 1) * BS)[l];

    float* op = orow + BS;  // row k (walked by 4*BS per round)

    int k = 1;
    #pragma unroll 1
    for (; k + 3 < n; k += 4) {
        // prefetch next round's f rows, scalar-clamped (no vector guards)
        const float pf0 = (frow + (size_t)imin(k + 5, n - 1) * BS)[l];
        const float pf1 = (frow + (size_t)imin(k + 6, n - 1) * BS)[l];
        const float pf2 = (frow + (size_t)imin(k + 7, n - 1) * BS)[l];
        const float pf3 = (frow + (size_t)imin(k + 8, n - 1) * BS)[l];

        // speculative midpoints with carried tanh (R13 numerics, verbatim)
        const float d0 = fR0 - tcar;
        const float s0 = fmaf(0.5f * DT_C, d0, yprev);
        const float yp0 = fmaf(DT_C, d0, yprev);
        const float d1 = fR1 - tcar;
        const float s1 = fmaf(0.5f * DT_C, d1, yp0);
        const float yp1 = fmaf(DT_C, d1, yp0);
        const float d2 = fR2 - tcar;
        const float s2 = fmaf(0.5f * DT_C, d2, yp1);
        const float yp2 = fmaf(DT_C, d2, yp1);
        const float d3 = fR3 - tcar;
        const float s3 = fmaf(0.5f * DT_C, d3, yp2);
        const float yp3 = fmaf(DT_C, d3, yp2);
        const float d4 = fR4 - tcar;
        const float s4 = fmaf(0.5f * DT_C, d4, yp3);  // PREVIEW midpoint k+4

        matvec5_mfma(lds_s, lds_u, wb, l, s0, s1, s2, s3, s4,
                     u0, u1, u2, u3, u4);

        const float r0 = recip_fast(exp2_fast(u0) + 1.0f);
        const float r1 = recip_fast(exp2_fast(u1) + 1.0f);
        const float r2 = recip_fast(exp2_fast(u2) + 1.0f);
        const float r3 = recip_fast(exp2_fast(u3) + 1.0f);
        const float r4 = recip_fast(exp2_fast(u4) + 1.0f);

        // exact-recurrence corrections with fresh tanh
        const float y1c = fmaf(2.0f * DT_C, r0, fmaf(DT_C, fR0, yprev) - DT_C);
        const float y2c = fmaf(2.0f * DT_C, r1, fmaf(DT_C, fR1, y1c) - DT_C);
        const float y3c = fmaf(2.0f * DT_C, r2, fmaf(DT_C, fR2, y2c) - DT_C);
        const float y4c = fmaf(2.0f * DT_C, r3, fmaf(DT_C, fR3, y3c) - DT_C);

        // stores: uniform row pointers + per-lane l (saddr form)
        op[l] = y1c;
        (op + BS)[l] = y2c;
        (op + 2 * BS)[l] = y3c;
        (op + 3 * BS)[l] = y4c;
        op += 4 * BS;

        yprev = y4c;
        tcar = fmaf(-2.0f, r4, 1.0f);  // preview tanh -> next round's carry
        fR0 = fR4; fR1 = pf0; fR2 = pf1; fR3 = pf2; fR4 = pf3;
    }

    // generic 1-step tail (not hit for n=65)
    #pragma unroll 1
    for (; k < n; ++k) {
        const float s = fmaf(0.5f * DT_C, fR0 - tcar, yprev);
        matvec5_mfma(lds_s, lds_u, wb, l, s, s, s, s, s, u0, u1, u2, u3, u4);
        const float r = recip_fast(exp2_fast(u0) + 1.0f);
        const float y = fmaf(2.0f * DT_C, r, fmaf(DT_C, fR0, yprev) - DT_C);
        op[l] = y;
        op += BS;
        yprev = y;
        tcar = fmaf(-2.0f, r, 1.0f);
        fR0 = fR1; fR1 = fR2; fR2 = fR3; fR3 = fR4;
    }
}

extern "C" void kernel_launch(void* const* d_in, const int* in_sizes, int n_in,
                              void* d_out, int out_size, void* d_ws, size_t ws_size,
                              hipStream_t stream) {
    const float* y0     = (const float*)d_in[0];   // (B, S)
    const float* forces = (const float*)d_in[1];   // (n, B, S)
    const float* W      = (const float*)d_in[2];   // (S, S)
    float* out = (float*)d_out;                    // (n, B, S)

    const int BS = in_sizes[0];       // B * S
    const int B  = BS / SDIM;         // 128
    const int n  = in_sizes[1] / BS;  // 65

    rnes_seq_kernel<<<B, SDIM, 0, stream>>>(y0, forces, W, out, n, B);
}